// Round 14
// baseline (1901.758 us; speedup 1.0000x reference)
//
#include <hip/hip_runtime.h>
#include <hip/hip_bf16.h>
#include <stdint.h>

#define NTOK 8192   // B*S
#define MDIM 1024
#define HDIM 4096
#define NEXP 8
#define CAP  2048   // int(1.0 * 2 * 8192 // 8)

typedef __attribute__((ext_vector_type(8))) short bf16x8;
typedef __attribute__((ext_vector_type(4))) float f32x4;

__device__ __forceinline__ ushort f2bf(float f) {
  uint32_t u = __builtin_bit_cast(uint32_t, f);
  u += 0x7FFFu + ((u >> 16) & 1u);          // round-to-nearest-even
  return (ushort)(u >> 16);
}
__device__ __forceinline__ float bf2f(ushort h) {
  uint32_t u = ((uint32_t)h) << 16;
  return __builtin_bit_cast(float, u);
}

// async global->LDS, 16B per lane; LDS dest = wave-uniform base + lane*16
#define GLOAD_LDS16(g, l)                                                    \
  __builtin_amdgcn_global_load_lds(                                          \
      (const __attribute__((address_space(1))) void*)(g),                    \
      (__attribute__((address_space(3))) void*)(l), 16, 0, 0)

// ---------------- gate: logits = x@wg (f64 accum), softmax-top2, normalize ----
__global__ __launch_bounds__(256) void gate_kernel(const float* __restrict__ x,
                                                   const float* __restrict__ wg,
                                                   int* __restrict__ topi,
                                                   float* __restrict__ gatev) {
  const int lane = threadIdx.x & 63;
  const int n = blockIdx.x * 4 + (threadIdx.x >> 6);   // one wave per token
  const float* xr = x + (size_t)n * MDIM;
  double acc[NEXP];
#pragma unroll
  for (int e = 0; e < NEXP; ++e) acc[e] = 0.0;
#pragma unroll
  for (int c = 0; c < 4; ++c) {
    float4 xv = *(const float4*)(xr + c * 256 + lane * 4);
    float xs[4] = {xv.x, xv.y, xv.z, xv.w};
#pragma unroll
    for (int j = 0; j < 4; ++j) {
      int m = c * 256 + lane * 4 + j;
      float4 w0 = *(const float4*)(wg + m * 8);
      float4 w1 = *(const float4*)(wg + m * 8 + 4);
      double xd = (double)xs[j];
      acc[0] += xd * (double)w0.x; acc[1] += xd * (double)w0.y;
      acc[2] += xd * (double)w0.z; acc[3] += xd * (double)w0.w;
      acc[4] += xd * (double)w1.x; acc[5] += xd * (double)w1.y;
      acc[6] += xd * (double)w1.z; acc[7] += xd * (double)w1.w;
    }
  }
#pragma unroll
  for (int off = 32; off >= 1; off >>= 1) {
#pragma unroll
    for (int e = 0; e < NEXP; ++e) acc[e] += __shfl_xor(acc[e], off, 64);
  }
  if (lane == 0) {
    int i0 = 0;
#pragma unroll
    for (int e = 1; e < NEXP; ++e) if (acc[e] > acc[i0]) i0 = e;
    int i1 = (i0 == 0) ? 1 : 0;
#pragma unroll
    for (int e = 0; e < NEXP; ++e) if (e != i0 && acc[e] > acc[i1]) i1 = e;
    // normalized top-2 of softmax == softmax over the two logits
    double e1 = exp(acc[i1] - acc[i0]);
    double s = 1.0 + e1;
    topi[n * 2 + 0] = i0; topi[n * 2 + 1] = i1;
    gatev[n * 2 + 0] = (float)(1.0 / s);
    gatev[n * 2 + 1] = (float)(e1 / s);
  }
}

// ---------------- slot-major cumulative positions (order: j = k*NTOK + n) ----
__global__ __launch_bounds__(256) void scan_kernel(const int* __restrict__ topi,
                                                   int* __restrict__ pos) {
  __shared__ int cnt[256][NEXP];
  const int t = threadIdx.x;
#pragma unroll
  for (int e = 0; e < NEXP; ++e) cnt[t][e] = 0;
  for (int i = 0; i < 64; ++i) {
    int j = t * 64 + i;
    int e = topi[(j & (NTOK - 1)) * 2 + (j >> 13)];
    cnt[t][e]++;
  }
  __syncthreads();
  if (t < NEXP) {          // exclusive scan over the 256 thread-chunks
    int run = 0;
    for (int i = 0; i < 256; ++i) { int v = cnt[i][t]; cnt[i][t] = run; run += v; }
  }
  __syncthreads();
  for (int i = 0; i < 64; ++i) {
    int j = t * 64 + i;
    int idx = (j & (NTOK - 1)) * 2 + (j >> 13);
    int e = topi[idx];
    pos[idx] = cnt[t][e]++;
  }
}

// ---------------- scatter x rows (bf16) into [E,CAP,M] -----------------------
// No zero-fill of disp needed: rows p >= count[e] are garbage, but the GEMMs
// are row-independent and combine only gathers pos < count[e] <= CAP slots --
// garbage rows are never read by any consumer of the final output.
__global__ __launch_bounds__(256) void scatter_kernel(const float* __restrict__ x,
                                                      const int* __restrict__ topi,
                                                      const int* __restrict__ pos,
                                                      ushort* __restrict__ disp) {
  const int lane = threadIdx.x & 63;
  const int n = blockIdx.x * 4 + (threadIdx.x >> 6);
  const float* src = x + (size_t)n * MDIM;
  ushort b[16];
#pragma unroll
  for (int c = 0; c < 4; ++c) {
    float4 v = *(const float4*)(src + c * 256 + lane * 4);
    b[c * 4 + 0] = f2bf(v.x); b[c * 4 + 1] = f2bf(v.y);
    b[c * 4 + 2] = f2bf(v.z); b[c * 4 + 3] = f2bf(v.w);
  }
#pragma unroll
  for (int k = 0; k < 2; ++k) {
    int p = pos[n * 2 + k];
    if (p < CAP) {
      int e = topi[n * 2 + k];
      ushort* dst = disp + ((size_t)(e * CAP + p)) * MDIM;
#pragma unroll
      for (int c = 0; c < 4; ++c) {
        ushort4 o; o.x = b[c*4+0]; o.y = b[c*4+1]; o.z = b[c*4+2]; o.w = b[c*4+3];
        *(ushort4*)(dst + c * 256 + lane * 4) = o;
      }
    }
  }
}

// ---------------- transpose + f32->bf16: in[R][C] -> out[C][R], per expert ---
__global__ __launch_bounds__(256) void transpose_cvt(const float* __restrict__ in,
                                                     ushort* __restrict__ out,
                                                     int R, int C) {
  __shared__ float tile[64][65];
  const int e = blockIdx.z;
  in  += (size_t)e * R * C;
  out += (size_t)e * R * C;
  const int r0 = blockIdx.y * 64, c0 = blockIdx.x * 64;
  const int t = threadIdx.x;
  const int r = t >> 2, cq = t & 3;
#pragma unroll
  for (int i = 0; i < 4; ++i) {
    float4 v = *(const float4*)(in + (size_t)(r0 + r) * C + c0 + cq * 16 + i * 4);
    tile[r][cq * 16 + i * 4 + 0] = v.x; tile[r][cq * 16 + i * 4 + 1] = v.y;
    tile[r][cq * 16 + i * 4 + 2] = v.z; tile[r][cq * 16 + i * 4 + 3] = v.w;
  }
  __syncthreads();
  const int oc = t >> 2, orr0 = (t & 3) * 16;
  ushort o16[16];
#pragma unroll
  for (int i = 0; i < 16; ++i) o16[i] = f2bf(tile[orr0 + i][oc]);
  ushort* dst = out + (size_t)(c0 + oc) * R + r0 + orr0;
  *(uint4*)dst = *(uint4*)&o16[0];
  *(uint4*)(dst + 8) = *(uint4*)&o16[8];
}

// ============================================================================
// 256x256x64 bf16 GEMM, one-window-ahead register prefetch (round 14):
// Root cause of the 40% plateau (11 variants): every wave's MFMA window
// consumed frags read in the SAME window, so the counted lgkm wait still
// blocked on the post-barrier read burst -> LDS drain (2304cy) and MFMA
// (2480cy) strictly alternated (measured: tile ~= their SUM in all rounds).
// Fix: TWO frag sets. Window W(T): READ(T+1) into idle set; STAGE(T+2);
// MFMA(T) from the set read LAST window -- its operands returned long ago
// (in-order LDS), so the wait is satisfiable with all 24 new reads still
// outstanding; they drain UNDER the 64 MFMAs. One SB pins reads+stages
// before MFMAs (round-8's per-cluster SBs avoided); 1 barrier + 1 VM0 per
// window (VM0 drains loads issued ~2400cy earlier -> ~0 stall).
// Ledger: buf0 read in odd windows / staged in even windows (1 barrier
// apart), symmetric buf1; prologue double-BAR protects tile-0 reads from
// W(0)'s STAGE(2)->buf0. Registers: 2x96 frag + ~30 addr VGPR, acc[8][4]
// in AGPR (round 12: VGPR_Count=128 proves compiler AGPRs the acc).
// ============================================================================
template <bool RELU>
__global__ __launch_bounds__(512, 1) void gemmpf(const ushort* __restrict__ Ag,
                                                 const ushort* __restrict__ Btg,
                                                 const float* __restrict__ biasg,
                                                 ushort* __restrict__ Cout,
                                                 int Mrows, int Ncols, int Kdim) {
  __shared__ ushort sh[65536];   // 128 KiB
  // bijective XCD swizzle (grids are %8==0)
  const int gx = gridDim.x, gy = gridDim.y;
  const int nwg = gx * gy * gridDim.z;
  const int lin = blockIdx.x + gx * (blockIdx.y + gy * blockIdx.z);
  const int cpx = nwg >> 3;
  const int swz = (lin & 7) * cpx + (lin >> 3);
  const int gxy = gx * gy;
  const int ez = swz / gxy;
  const int rem = swz - ez * gxy;
  const int by = rem / gx;
  const int bx = rem - by * gx;

  const ushort* A  = Ag  + (size_t)ez * Mrows * Kdim;
  const ushort* Bt = Btg + (size_t)ez * Ncols * Kdim;
  const float* bias = biasg + (size_t)ez * Ncols;
  ushort* Cptr = Cout + (size_t)ez * Mrows * Ncols;
  const int m0 = by * 256, n0 = bx * 256;
  const int t = threadIdx.x, lane = t & 63, w = t >> 6;
  const int l15 = lane & 15, l4 = lane >> 4;
  const int wr = w >> 2, wc = w & 3;      // 2x4 wave grid

  // ---- staging addressing (verified rounds 2-13) ----
  const int srow = lane >> 3;             // 0..7 row within 8-row slab
  const int cs = (lane & 7) ^ srow;       // pre-swizzled source chunk
  const ushort* Abase = A  + (size_t)(m0 + w * 8 + srow) * Kdim + cs * 8;
  const ushort* Bbase = Bt + (size_t)(n0 + w * 8 + srow) * Kdim + cs * 8;
  const int ldsw = w * 512;               // wave-uniform LDS offset (ushorts)

#define STAGE8(isA, d, half, ktile)                                          \
  do {                                                                       \
    const ushort* gb = ((isA) ? Abase : Bbase) +                             \
                       (size_t)((half) * 128) * Kdim + (ktile) * 64;         \
    ushort* lb = sh + ((isA) ? 0 : 32768) + ((d) * 2 + (half)) * 8192 + ldsw;\
    GLOAD_LDS16(gb, lb);                                                     \
    GLOAD_LDS16(gb + (size_t)64 * Kdim, lb + 4096);                         \
  } while (0)

#define STAGE_T(d, ktile)                                                    \
  do { STAGE8(1, d, 0, ktile); STAGE8(1, d, 1, ktile);                       \
       STAGE8(0, d, 0, ktile); STAGE8(0, d, 1, ktile); } while (0)

  // ---- fragment-read addressing (conflict-free l15/l4 pattern) ----
  const int chk0 = ((0 + l4) ^ (l15 & 7)) * 8;   // kk=0 chunk (ushorts)
  const int chk1 = ((4 + l4) ^ (l15 & 7)) * 8;   // kk=1 chunk
  const int aoff = (wr * 64 + l15) * 64;
  const int boff = (wc * 32 + l15) * 64;

  // two full-tile frag sets (A: [fr]=kk0,[4+fr]=kk1; B: [fc]=kk0,[2+fc]=kk1)
  bf16x8 a0A[8], a1A[8], b0A[4], b1A[4];   // set A (even tiles)
  bf16x8 a0B[8], a1B[8], b0B[4], b1B[4];   // set B (odd tiles)

#define READ_T(d, A0, A1, B0, B1)                                            \
  { const ushort* Ar0 = sh + ((d) * 2 + 0) * 8192 + aoff;                    \
    const ushort* Ar1 = sh + ((d) * 2 + 1) * 8192 + aoff;                    \
    _Pragma("unroll") for (int fr = 0; fr < 4; ++fr) {                       \
      A0[fr]     = *(const bf16x8*)(Ar0 + fr * 1024 + chk0);                 \
      A0[4 + fr] = *(const bf16x8*)(Ar0 + fr * 1024 + chk1);                 \
      A1[fr]     = *(const bf16x8*)(Ar1 + fr * 1024 + chk0);                 \
      A1[4 + fr] = *(const bf16x8*)(Ar1 + fr * 1024 + chk1);                 \
    }                                                                        \
    const ushort* Br0 = sh + 32768 + ((d) * 2 + 0) * 8192 + boff;            \
    const ushort* Br1 = sh + 32768 + ((d) * 2 + 1) * 8192 + boff;            \
    _Pragma("unroll") for (int fc = 0; fc < 2; ++fc) {                       \
      B0[fc]     = *(const bf16x8*)(Br0 + fc * 1024 + chk0);                 \
      B0[2 + fc] = *(const bf16x8*)(Br0 + fc * 1024 + chk1);                 \
      B1[fc]     = *(const bf16x8*)(Br1 + fc * 1024 + chk0);                 \
      B1[2 + fc] = *(const bf16x8*)(Br1 + fc * 1024 + chk1);                 \
    } }

#define MM(d, s, a, b) d = __builtin_amdgcn_mfma_f32_16x16x32_bf16(a, b, s, 0, 0, 0)
#define MFMA_T(A0, A1, B0, B1)                                               \
  __builtin_amdgcn_s_setprio(1);                                             \
  _Pragma("unroll") for (int fr = 0; fr < 4; ++fr)                           \
    _Pragma("unroll") for (int fc = 0; fc < 2; ++fc) {                       \
      MM(acc[fr][fc],         acc[fr][fc],         A0[fr],     B0[fc]);      \
      MM(acc[fr][fc],         acc[fr][fc],         A0[4 + fr], B0[2 + fc]);  \
      MM(acc[fr][2 + fc],     acc[fr][2 + fc],     A0[fr],     B1[fc]);      \
      MM(acc[fr][2 + fc],     acc[fr][2 + fc],     A0[4 + fr], B1[2 + fc]);  \
      MM(acc[4 + fr][fc],     acc[4 + fr][fc],     A1[fr],     B0[fc]);      \
      MM(acc[4 + fr][fc],     acc[4 + fr][fc],     A1[4 + fr], B0[2 + fc]);  \
      MM(acc[4 + fr][2 + fc], acc[4 + fr][2 + fc], A1[fr],     B1[fc]);      \
      MM(acc[4 + fr][2 + fc], acc[4 + fr][2 + fc], A1[4 + fr], B1[2 + fc]);  \
    }                                                                        \
  __builtin_amdgcn_s_setprio(0);

#define SB  __builtin_amdgcn_sched_barrier(0)
#define BAR __builtin_amdgcn_s_barrier()
#define VM0 asm volatile("s_waitcnt vmcnt(0)" ::: "memory")

  f32x4 acc[8][4];
#pragma unroll
  for (int i = 0; i < 8; ++i)
#pragma unroll
    for (int j = 0; j < 4; ++j) acc[i][j] = (f32x4){0.f, 0.f, 0.f, 0.f};

  const int NT = Kdim >> 6;   // 16 or 64 (even)
  // prologue: stage tiles 0,1; drain; read tile 0 frags; barrier (protects
  // buf0 from W(0)'s STAGE(2) -- reads and that stage are 1 barrier apart)
  STAGE_T(0, 0);
  STAGE_T(1, 1);
  VM0; SB; BAR;
  READ_T(0, a0A, a1A, b0A, b1A)
  SB; BAR;

  for (int i2 = 0; i2 < (NT >> 1); ++i2) {
    const int T = 2 * i2;
    const bool s0 = (T + 2) < NT;
    const bool s1 = (T + 3) < NT;
    const bool last = (i2 == (NT >> 1) - 1);
    // ---- W(T) even: read T+1 (buf1) into set B; stage T+2 -> buf0;
    //      MFMA tile T from set A (read last window) ----
    READ_T(1, a0B, a1B, b0B, b1B)
    if (s0) STAGE_T(0, T + 2);
    SB;                                  // pin prefetch before MFMAs
    MFMA_T(a0A, a1A, b0A, b1A)
    SB; VM0; BAR;                        // T+2 staged -> readable next window
    // ---- W(T+1) odd: read T+2 (buf0) into set A; stage T+3 -> buf1;
    //      MFMA tile T+1 from set B ----
    if (s0) { READ_T(0, a0A, a1A, b0A, b1A) }
    if (s1) STAGE_T(1, T + 3);
    SB;
    MFMA_T(a0B, a1B, b0B, b1B)
    if (!last) { SB; VM0; BAR; }
  }

  // epilogue: D[row=(l>>4)*4+r][col=l&15] per 16x16 frag
#pragma unroll
  for (int ai = 0; ai < 2; ++ai)
#pragma unroll
    for (int fr = 0; fr < 4; ++fr) {
      const int rowb = m0 + ai * 128 + wr * 64 + fr * 16 + l4 * 4;
#pragma unroll
      for (int bj = 0; bj < 2; ++bj)
#pragma unroll
        for (int fc = 0; fc < 2; ++fc) {
          const int col = n0 + bj * 128 + wc * 32 + fc * 16 + l15;
          const float bv = bias[col];
          f32x4 v = acc[ai * 4 + fr][bj * 2 + fc];
#pragma unroll
          for (int r = 0; r < 4; ++r) {
            float f = v[r] + bv;
            if (RELU) f = fmaxf(f, 0.f);
            Cptr[(size_t)(rowb + r) * Ncols + col] = f2bf(f);
          }
        }
    }
#undef STAGE8
#undef STAGE_T
#undef READ_T
#undef MM
#undef MFMA_T
#undef SB
#undef BAR
#undef VM0
}

// ---------------- combine: out[n] = sum_k gate * y[e_k, p_k] -----------------
__global__ __launch_bounds__(256) void combine_kernel(const ushort* __restrict__ y,
                                                      const int* __restrict__ topi,
                                                      const int* __restrict__ pos,
                                                      const float* __restrict__ gatev,
                                                      float* __restrict__ out) {
  const int lane = threadIdx.x & 63;
  const int n = blockIdx.x * 4 + (threadIdx.x >> 6);
  int i0 = topi[n * 2], i1 = topi[n * 2 + 1];
  int p0 = pos[n * 2], p1 = pos[n * 2 + 1];
  float g0 = (p0 < CAP) ? gatev[n * 2] : 0.f;
  float g1 = (p1 < CAP) ? gatev[n * 2 + 1] : 0.f;
  const ushort* y0 = y + (size_t)(i0 * CAP + (p0 < CAP ? p0 : 0)) * MDIM;
  const ushort* y1 = y + (size_t)(i1 * CAP + (p1 < CAP ? p1 : 0)) * MDIM;
  float* o = out + (size_t)n * MDIM;
#pragma unroll
  for (int c = 0; c < 4; ++c) {
    int idx = c * 256 + lane * 4;
    ushort4 a = *(const ushort4*)(y0 + idx);
    ushort4 b = *(const ushort4*)(y1 + idx);
    float4 ov;
    ov.x = g0 * bf2f(a.x) + g1 * bf2f(b.x);
    ov.y = g0 * bf2f(a.y) + g1 * bf2f(b.y);
    ov.z = g0 * bf2f(a.z) + g1 * bf2f(b.z);
    ov.w = g0 * bf2f(a.w) + g1 * bf2f(b.w);
    *(float4*)(o + idx) = ov;
  }
}

extern "C" void kernel_launch(void* const* d_in, const int* in_sizes, int n_in,
                              void* d_out, int out_size, void* d_ws, size_t ws_size,
                              hipStream_t stream) {
  const float* x  = (const float*)d_in[0];
  const float* wg = (const float*)d_in[1];
  const float* w1 = (const float*)d_in[2];
  const float* b1 = (const float*)d_in[3];
  const float* w2 = (const float*)d_in[4];
  const float* b2 = (const float*)d_in[5];
  float* out = (float*)d_out;
  char* ws = (char*)d_ws;

  // workspace layout (224.3 MB total)
  int*    topi  = (int*)(ws);
  int*    pos   = (int*)(ws + 65536);
  float*  gatev = (float*)(ws + 131072);
  ushort* dispb = (ushort*)(ws + 262144);                          // 32MB, reused as y
  ushort* wT    = (ushort*)(ws + 262144 + 33554432);               // 64MB (w1t then w2t)
  ushort* hbuf  = (ushort*)(ws + 262144 + 33554432 + 67108864);    // 128MB

  gate_kernel<<<NTOK / 4, 256, 0, stream>>>(x, wg, topi, gatev);
  scan_kernel<<<1, 256, 0, stream>>>(topi, pos);
  // no zero_kernel: disp rows p >= count[e] are never read downstream
  scatter_kernel<<<NTOK / 4, 256, 0, stream>>>(x, topi, pos, dispb);

  // FFN layer 1: h = relu(disp @ w1 + b1)   [E,2048,1024]x[E,1024,4096]
  transpose_cvt<<<dim3(HDIM / 64, MDIM / 64, NEXP), 256, 0, stream>>>(w1, wT, MDIM, HDIM);
  gemmpf<true><<<dim3(HDIM / 256, CAP / 256, NEXP), 512, 0, stream>>>(
      dispb, wT, b1, hbuf, CAP, HDIM, MDIM);

  // FFN layer 2: y = h @ w2 + b2            [E,2048,4096]x[E,4096,1024]
  transpose_cvt<<<dim3(MDIM / 64, HDIM / 64, NEXP), 256, 0, stream>>>(w2, wT, HDIM, MDIM);
  ushort* ybuf = dispb;  // dispb is dead after GEMM1
  gemmpf<false><<<dim3(MDIM / 256, CAP / 256, NEXP), 512, 0, stream>>>(
      hbuf, wT, b2, ybuf, CAP, MDIM, HDIM);

  combine_kernel<<<NTOK / 4, 256, 0, stream>>>(ybuf, topi, pos, gatev, out);
}

// Round 15
// 411.558 us; speedup vs baseline: 4.6209x; 4.6209x over previous
//
#include <hip/hip_runtime.h>
#include <hip/hip_bf16.h>
#include <stdint.h>

#define NTOK 8192   // B*S
#define MDIM 1024
#define HDIM 4096
#define NEXP 8
#define CAP  2048   // int(1.0 * 2 * 8192 // 8)

typedef __attribute__((ext_vector_type(8))) short bf16x8;
typedef __attribute__((ext_vector_type(4))) float f32x4;

__device__ __forceinline__ ushort f2bf(float f) {
  uint32_t u = __builtin_bit_cast(uint32_t, f);
  u += 0x7FFFu + ((u >> 16) & 1u);          // round-to-nearest-even
  return (ushort)(u >> 16);
}
__device__ __forceinline__ float bf2f(ushort h) {
  uint32_t u = ((uint32_t)h) << 16;
  return __builtin_bit_cast(float, u);
}

// async global->LDS, 16B per lane; LDS dest = wave-uniform base + lane*16
#define GLOAD_LDS16(g, l)                                                    \
  __builtin_amdgcn_global_load_lds(                                          \
      (const __attribute__((address_space(1))) void*)(g),                    \
      (__attribute__((address_space(3))) void*)(l), 16, 0, 0)

// ---------------- gate: logits = x@wg (f64 accum), softmax-top2, normalize ----
__global__ __launch_bounds__(256) void gate_kernel(const float* __restrict__ x,
                                                   const float* __restrict__ wg,
                                                   int* __restrict__ topi,
                                                   float* __restrict__ gatev) {
  const int lane = threadIdx.x & 63;
  const int n = blockIdx.x * 4 + (threadIdx.x >> 6);   // one wave per token
  const float* xr = x + (size_t)n * MDIM;
  double acc[NEXP];
#pragma unroll
  for (int e = 0; e < NEXP; ++e) acc[e] = 0.0;
#pragma unroll
  for (int c = 0; c < 4; ++c) {
    float4 xv = *(const float4*)(xr + c * 256 + lane * 4);
    float xs[4] = {xv.x, xv.y, xv.z, xv.w};
#pragma unroll
    for (int j = 0; j < 4; ++j) {
      int m = c * 256 + lane * 4 + j;
      float4 w0 = *(const float4*)(wg + m * 8);
      float4 w1 = *(const float4*)(wg + m * 8 + 4);
      double xd = (double)xs[j];
      acc[0] += xd * (double)w0.x; acc[1] += xd * (double)w0.y;
      acc[2] += xd * (double)w0.z; acc[3] += xd * (double)w0.w;
      acc[4] += xd * (double)w1.x; acc[5] += xd * (double)w1.y;
      acc[6] += xd * (double)w1.z; acc[7] += xd * (double)w1.w;
    }
  }
#pragma unroll
  for (int off = 32; off >= 1; off >>= 1) {
#pragma unroll
    for (int e = 0; e < NEXP; ++e) acc[e] += __shfl_xor(acc[e], off, 64);
  }
  if (lane == 0) {
    int i0 = 0;
#pragma unroll
    for (int e = 1; e < NEXP; ++e) if (acc[e] > acc[i0]) i0 = e;
    int i1 = (i0 == 0) ? 1 : 0;
#pragma unroll
    for (int e = 0; e < NEXP; ++e) if (e != i0 && acc[e] > acc[i1]) i1 = e;
    // normalized top-2 of softmax == softmax over the two logits
    double e1 = exp(acc[i1] - acc[i0]);
    double s = 1.0 + e1;
    topi[n * 2 + 0] = i0; topi[n * 2 + 1] = i1;
    gatev[n * 2 + 0] = (float)(1.0 / s);
    gatev[n * 2 + 1] = (float)(e1 / s);
  }
}

// ---------------- slot-major cumulative positions (order: j = k*NTOK + n) ----
__global__ __launch_bounds__(256) void scan_kernel(const int* __restrict__ topi,
                                                   int* __restrict__ pos) {
  __shared__ int cnt[256][NEXP];
  const int t = threadIdx.x;
#pragma unroll
  for (int e = 0; e < NEXP; ++e) cnt[t][e] = 0;
  for (int i = 0; i < 64; ++i) {
    int j = t * 64 + i;
    int e = topi[(j & (NTOK - 1)) * 2 + (j >> 13)];
    cnt[t][e]++;
  }
  __syncthreads();
  if (t < NEXP) {          // exclusive scan over the 256 thread-chunks
    int run = 0;
    for (int i = 0; i < 256; ++i) { int v = cnt[i][t]; cnt[i][t] = run; run += v; }
  }
  __syncthreads();
  for (int i = 0; i < 64; ++i) {
    int j = t * 64 + i;
    int idx = (j & (NTOK - 1)) * 2 + (j >> 13);
    int e = topi[idx];
    pos[idx] = cnt[t][e]++;
  }
}

// ---------------- scatter x rows (bf16) into [E,CAP,M] -----------------------
// No zero-fill of disp needed: rows p >= count[e] are garbage, but the GEMMs
// are row-independent and combine only gathers pos < count[e] <= CAP slots --
// garbage rows are never read by any consumer of the final output.
__global__ __launch_bounds__(256) void scatter_kernel(const float* __restrict__ x,
                                                      const int* __restrict__ topi,
                                                      const int* __restrict__ pos,
                                                      ushort* __restrict__ disp) {
  const int lane = threadIdx.x & 63;
  const int n = blockIdx.x * 4 + (threadIdx.x >> 6);
  const float* src = x + (size_t)n * MDIM;
  ushort b[16];
#pragma unroll
  for (int c = 0; c < 4; ++c) {
    float4 v = *(const float4*)(src + c * 256 + lane * 4);
    b[c * 4 + 0] = f2bf(v.x); b[c * 4 + 1] = f2bf(v.y);
    b[c * 4 + 2] = f2bf(v.z); b[c * 4 + 3] = f2bf(v.w);
  }
#pragma unroll
  for (int k = 0; k < 2; ++k) {
    int p = pos[n * 2 + k];
    if (p < CAP) {
      int e = topi[n * 2 + k];
      ushort* dst = disp + ((size_t)(e * CAP + p)) * MDIM;
#pragma unroll
      for (int c = 0; c < 4; ++c) {
        ushort4 o; o.x = b[c*4+0]; o.y = b[c*4+1]; o.z = b[c*4+2]; o.w = b[c*4+3];
        *(ushort4*)(dst + c * 256 + lane * 4) = o;
      }
    }
  }
}

// ---------------- transpose + f32->bf16: in[R][C] -> out[C][R], per expert ---
__global__ __launch_bounds__(256) void transpose_cvt(const float* __restrict__ in,
                                                     ushort* __restrict__ out,
                                                     int R, int C) {
  __shared__ float tile[64][65];
  const int e = blockIdx.z;
  in  += (size_t)e * R * C;
  out += (size_t)e * R * C;
  const int r0 = blockIdx.y * 64, c0 = blockIdx.x * 64;
  const int t = threadIdx.x;
  const int r = t >> 2, cq = t & 3;
#pragma unroll
  for (int i = 0; i < 4; ++i) {
    float4 v = *(const float4*)(in + (size_t)(r0 + r) * C + c0 + cq * 16 + i * 4);
    tile[r][cq * 16 + i * 4 + 0] = v.x; tile[r][cq * 16 + i * 4 + 1] = v.y;
    tile[r][cq * 16 + i * 4 + 2] = v.z; tile[r][cq * 16 + i * 4 + 3] = v.w;
  }
  __syncthreads();
  const int oc = t >> 2, orr0 = (t & 3) * 16;
  ushort o16[16];
#pragma unroll
  for (int i = 0; i < 16; ++i) o16[i] = f2bf(tile[orr0 + i][oc]);
  ushort* dst = out + (size_t)(c0 + oc) * R + r0 + orr0;
  *(uint4*)dst = *(uint4*)&o16[0];
  *(uint4*)(dst + 8) = *(uint4*)&o16[8];
}

// ============================================================================
// 256x256x64 bf16 GEMM, merged-window schedule (round 15 = round 12 revert,
// the banked best: total 410.3us; GEMM dispatches 137-145us across identical
// runs = documented +-3% noise band; MfmaUtil 40-43%, 0 bank conflicts,
// VGPR 128 w/ acc in AGPR).
// 14-round conclusion: the 8-wave 256^2 structure is pinned at ~40% MfmaUtil
// by register capacity vs LDS traffic: same-window frags (64 VGPR) make LDS
// burst and MFMA alternate (tile ~= 2304 + 2480 cy sum); one-window-ahead
// frags need ~220 VGPR and spill to scratch (round 14: 6% MfmaUtil, 16x
// WRITE_SIZE). Alternatives measured and rejected: free-run barriers (r6),
// 32x32 MFMA (r7, bank conflicts), cluster pipeline (r8), no-setprio (r9),
// 4-wave 128x128 builtin (r10, spill) and AGPR-asm (r11, spill), m201-exact
// lgkmcnt(0) phases (r13, kills counted-wait overlap).
// Quadrant walk q0=(A0,B0) q1=(A0,B1) q2=(A1,B1) q3=(A1,B0); A-frags held
// across pairs, B0 held q0->q3 (24 ds_read_b128/tile/wave = minimum).
// 2 windows/tile; counted VM4 (VM0 last iter); global_load_lds(16B) with
// pre-swizzled source, linear LDS dest, XOR-swizzled conflict-free reads.
// ============================================================================
template <bool RELU>
__global__ __launch_bounds__(512, 1) void gemm8p(const ushort* __restrict__ Ag,
                                                 const ushort* __restrict__ Btg,
                                                 const float* __restrict__ biasg,
                                                 ushort* __restrict__ Cout,
                                                 int Mrows, int Ncols, int Kdim) {
  __shared__ ushort sh[65536];   // 128 KiB
  // bijective XCD swizzle (grids are %8==0)
  const int gx = gridDim.x, gy = gridDim.y;
  const int nwg = gx * gy * gridDim.z;
  const int lin = blockIdx.x + gx * (blockIdx.y + gy * blockIdx.z);
  const int cpx = nwg >> 3;
  const int swz = (lin & 7) * cpx + (lin >> 3);
  const int gxy = gx * gy;
  const int ez = swz / gxy;
  const int rem = swz - ez * gxy;
  const int by = rem / gx;
  const int bx = rem - by * gx;

  const ushort* A  = Ag  + (size_t)ez * Mrows * Kdim;
  const ushort* Bt = Btg + (size_t)ez * Ncols * Kdim;
  const float* bias = biasg + (size_t)ez * Ncols;
  ushort* Cptr = Cout + (size_t)ez * Mrows * Ncols;
  const int m0 = by * 256, n0 = bx * 256;
  const int t = threadIdx.x, lane = t & 63, w = t >> 6;
  const int l15 = lane & 15, l4 = lane >> 4;
  const int wr = w >> 2, wc = w & 3;      // 2x4 wave grid over quadrant frags

  // ---- staging addressing ----
  const int srow = lane >> 3;             // 0..7 row within 8-row slab
  const int cs = (lane & 7) ^ srow;       // pre-swizzled source chunk
  const ushort* Abase = A  + (size_t)(m0 + w * 8 + srow) * Kdim + cs * 8;
  const ushort* Bbase = Bt + (size_t)(n0 + w * 8 + srow) * Kdim + cs * 8;
  const int ldsw = w * 512;               // wave-uniform LDS offset (ushorts)

  // stage one half (128 rows x 64 K) of A or B: 2 gloads/thread
#define STAGE8(isA, d, half, ktile)                                          \
  do {                                                                       \
    const ushort* gb = ((isA) ? Abase : Bbase) +                             \
                       (size_t)((half) * 128) * Kdim + (ktile) * 64;         \
    ushort* lb = sh + ((isA) ? 0 : 32768) + ((d) * 2 + (half)) * 8192 + ldsw;\
    GLOAD_LDS16(gb, lb);                                                     \
    GLOAD_LDS16(gb + (size_t)64 * Kdim, lb + 4096);                         \
  } while (0)

  // ---- fragment-read addressing ----
  const int chk0 = ((0 + l4) ^ (l15 & 7)) * 8;   // kk=0 chunk (ushorts)
  const int chk1 = ((4 + l4) ^ (l15 & 7)) * 8;   // kk=1 chunk
  const int aoff = (wr * 64 + l15) * 64;
  const int boff = (wc * 32 + l15) * 64;

  bf16x8 af[8];    // A-frags of current ai: [fr]=kk0, [4+fr]=kk1
  bf16x8 b0[4];    // B0 frags: [fc]=kk0, [2+fc]=kk1 (held q0->q3)
  bf16x8 b1[4];    // B1 frags

#define READ_A(d, ai)                                                        \
  { const ushort* Ar = sh + ((d) * 2 + (ai)) * 8192 + aoff;                  \
    _Pragma("unroll") for (int fr = 0; fr < 4; ++fr) {                       \
      af[fr]     = *(const bf16x8*)(Ar + fr * 1024 + chk0);                  \
      af[4 + fr] = *(const bf16x8*)(Ar + fr * 1024 + chk1);                  \
    } }

#define READ_B(d, bj, dst)                                                   \
  { const ushort* Br = sh + 32768 + ((d) * 2 + (bj)) * 8192 + boff;          \
    _Pragma("unroll") for (int fc = 0; fc < 2; ++fc) {                       \
      dst[fc]     = *(const bf16x8*)(Br + fc * 1024 + chk0);                 \
      dst[2 + fc] = *(const bf16x8*)(Br + fc * 1024 + chk1);                 \
    } }

#define MFMA_Q(ai, bj, BR)                                                   \
  __builtin_amdgcn_s_setprio(1);                                             \
  _Pragma("unroll") for (int fr = 0; fr < 4; ++fr)                           \
    _Pragma("unroll") for (int fc = 0; fc < 2; ++fc) {                       \
      acc[(ai) * 4 + fr][(bj) * 2 + fc] =                                    \
          __builtin_amdgcn_mfma_f32_16x16x32_bf16(                           \
              af[fr], BR[fc], acc[(ai) * 4 + fr][(bj) * 2 + fc], 0, 0, 0);   \
      acc[(ai) * 4 + fr][(bj) * 2 + fc] =                                    \
          __builtin_amdgcn_mfma_f32_16x16x32_bf16(                           \
              af[4 + fr], BR[2 + fc], acc[(ai) * 4 + fr][(bj) * 2 + fc],     \
              0, 0, 0);                                                      \
    }                                                                        \
  __builtin_amdgcn_s_setprio(0);

#define SB  __builtin_amdgcn_sched_barrier(0)
#define BAR __builtin_amdgcn_s_barrier()
#define VM4 asm volatile("s_waitcnt vmcnt(4)" ::: "memory")
#define VM0 asm volatile("s_waitcnt vmcnt(0)" ::: "memory")

  f32x4 acc[8][4];
#pragma unroll
  for (int i = 0; i < 8; ++i)
#pragma unroll
    for (int j = 0; j < 4; ++j) acc[i][j] = (f32x4){0.f, 0.f, 0.f, 0.f};

  const int NT = Kdim >> 6;
  const int NI = NT >> 1;
  // prologue: tile0 all 4 halves + tile1 A0,B1 (steady-state invariant)
  STAGE8(1, 0, 0, 0);
  STAGE8(0, 0, 1, 0);
  STAGE8(1, 0, 1, 0);
  STAGE8(0, 0, 0, 0);
  STAGE8(1, 1, 0, 1);
  STAGE8(0, 1, 1, 1);
  VM4;           // 12 outstanding -> drains tile0's 8; tile1 A0,B1 in flight
  SB; BAR;

  for (int t2 = 0; t2 < NI; ++t2) {
    const int tb = 2 * t2;
    const bool g2 = (t2 + 1) < NI;     // tiles tb+2, tb+3 exist
    const bool last = (t2 == NI - 1);
    // ---- W0: tile tb (buf0), q0+q1 ----
    READ_A(0, 0) READ_B(0, 0, b0)
    STAGE8(1, 1, 1, tb + 1);           // A1 of t+1 -> d1
    STAGE8(0, 1, 0, tb + 1);           // B0 of t+1 -> d1
    READ_B(0, 1, b1)
    MFMA_Q(0, 0, b0)
    MFMA_Q(0, 1, b1)
    SB; BAR;
    // ---- W1: tile tb, q2+q3 ----
    READ_A(0, 1)
    if (g2) { STAGE8(1, 0, 0, tb + 2); STAGE8(0, 0, 1, tb + 2); } // A0,B1 t+2 -> d0
    MFMA_Q(1, 1, b1)
    MFMA_Q(1, 0, b0)
    SB;
    if (last) { VM0; } else { VM4; }   // t+1 (d1) fully staged after this
    BAR;
    // ---- W2: tile tb+1 (buf1), q0+q1 ----
    READ_A(1, 0) READ_B(1, 0, b0)
    if (g2) { STAGE8(1, 0, 1, tb + 2); STAGE8(0, 0, 0, tb + 2); } // A1,B0 t+2 -> d0
    READ_B(1, 1, b1)
    MFMA_Q(0, 0, b0)
    MFMA_Q(0, 1, b1)
    SB; BAR;
    // ---- W3: tile tb+1, q2+q3 ----
    READ_A(1, 1)
    if (g2) { STAGE8(1, 1, 0, tb + 3); STAGE8(0, 1, 1, tb + 3); } // A0,B1 t+3 -> d1
    MFMA_Q(1, 1, b1)
    MFMA_Q(1, 0, b0)
    SB; VM4; BAR;                      // t+2 (d0) fully staged after this
  }

  // epilogue: D[row=(l>>4)*4+r][col=l&15] per 16x16 frag
#pragma unroll
  for (int ai = 0; ai < 2; ++ai)
#pragma unroll
    for (int fr = 0; fr < 4; ++fr) {
      const int rowb = m0 + ai * 128 + wr * 64 + fr * 16 + l4 * 4;
#pragma unroll
      for (int bj = 0; bj < 2; ++bj)
#pragma unroll
        for (int fc = 0; fc < 2; ++fc) {
          const int col = n0 + bj * 128 + wc * 32 + fc * 16 + l15;
          const float bv = bias[col];
          f32x4 v = acc[ai * 4 + fr][bj * 2 + fc];
#pragma unroll
          for (int r = 0; r < 4; ++r) {
            float f = v[r] + bv;
            if (RELU) f = fmaxf(f, 0.f);
            Cptr[(size_t)(rowb + r) * Ncols + col] = f2bf(f);
          }
        }
    }
#undef STAGE8
#undef READ_A
#undef READ_B
#undef MFMA_Q
#undef SB
#undef BAR
#undef VM4
#undef VM0
}

// ---------------- combine: out[n] = sum_k gate * y[e_k, p_k] -----------------
__global__ __launch_bounds__(256) void combine_kernel(const ushort* __restrict__ y,
                                                      const int* __restrict__ topi,
                                                      const int* __restrict__ pos,
                                                      const float* __restrict__ gatev,
                                                      float* __restrict__ out) {
  const int lane = threadIdx.x & 63;
  const int n = blockIdx.x * 4 + (threadIdx.x >> 6);
  int i0 = topi[n * 2], i1 = topi[n * 2 + 1];
  int p0 = pos[n * 2], p1 = pos[n * 2 + 1];
  float g0 = (p0 < CAP) ? gatev[n * 2] : 0.f;
  float g1 = (p1 < CAP) ? gatev[n * 2 + 1] : 0.f;
  const ushort* y0 = y + (size_t)(i0 * CAP + (p0 < CAP ? p0 : 0)) * MDIM;
  const ushort* y1 = y + (size_t)(i1 * CAP + (p1 < CAP ? p1 : 0)) * MDIM;
  float* o = out + (size_t)n * MDIM;
#pragma unroll
  for (int c = 0; c < 4; ++c) {
    int idx = c * 256 + lane * 4;
    ushort4 a = *(const ushort4*)(y0 + idx);
    ushort4 b = *(const ushort4*)(y1 + idx);
    float4 ov;
    ov.x = g0 * bf2f(a.x) + g1 * bf2f(b.x);
    ov.y = g0 * bf2f(a.y) + g1 * bf2f(b.y);
    ov.z = g0 * bf2f(a.z) + g1 * bf2f(b.z);
    ov.w = g0 * bf2f(a.w) + g1 * bf2f(b.w);
    *(float4*)(o + idx) = ov;
  }
}

extern "C" void kernel_launch(void* const* d_in, const int* in_sizes, int n_in,
                              void* d_out, int out_size, void* d_ws, size_t ws_size,
                              hipStream_t stream) {
  const float* x  = (const float*)d_in[0];
  const float* wg = (const float*)d_in[1];
  const float* w1 = (const float*)d_in[2];
  const float* b1 = (const float*)d_in[3];
  const float* w2 = (const float*)d_in[4];
  const float* b2 = (const float*)d_in[5];
  float* out = (float*)d_out;
  char* ws = (char*)d_ws;

  // workspace layout (224.3 MB total)
  int*    topi  = (int*)(ws);
  int*    pos   = (int*)(ws + 65536);
  float*  gatev = (float*)(ws + 131072);
  ushort* dispb = (ushort*)(ws + 262144);                          // 32MB, reused as y
  ushort* wT    = (ushort*)(ws + 262144 + 33554432);               // 64MB (w1t then w2t)
  ushort* hbuf  = (ushort*)(ws + 262144 + 33554432 + 67108864);    // 128MB

  gate_kernel<<<NTOK / 4, 256, 0, stream>>>(x, wg, topi, gatev);
  scan_kernel<<<1, 256, 0, stream>>>(topi, pos);
  // no zero_kernel: disp rows p >= count[e] are never read downstream
  scatter_kernel<<<NTOK / 4, 256, 0, stream>>>(x, topi, pos, dispb);

  // FFN layer 1: h = relu(disp @ w1 + b1)   [E,2048,1024]x[E,1024,4096]
  transpose_cvt<<<dim3(HDIM / 64, MDIM / 64, NEXP), 256, 0, stream>>>(w1, wT, MDIM, HDIM);
  gemm8p<true><<<dim3(HDIM / 256, CAP / 256, NEXP), 512, 0, stream>>>(
      dispb, wT, b1, hbuf, CAP, HDIM, MDIM);

  // FFN layer 2: y = h @ w2 + b2            [E,2048,4096]x[E,4096,1024]
  transpose_cvt<<<dim3(MDIM / 64, HDIM / 64, NEXP), 256, 0, stream>>>(w2, wT, HDIM, MDIM);
  ushort* ybuf = dispb;  // dispb is dead after GEMM1
  gemm8p<false><<<dim3(MDIM / 256, CAP / 256, NEXP), 512, 0, stream>>>(
      hbuf, wT, b2, ybuf, CAP, MDIM, HDIM);

  combine_kernel<<<NTOK / 4, 256, 0, stream>>>(ybuf, topi, pos, gatev, out);
}